// Round 1
// baseline (62.979 us; speedup 1.0000x reference)
//
#include <hip/hip_runtime.h>

// Problem: B=64, D=256, M=100
//   k(b,i,j) = 0.5 * sum_m (|f[b,i,m]+f[b,j,m]| - |f[b,i,m]-f[b,j,m]|) * exp(T)
//   out = k - rowmean_i - rowmean_j  (symmetric), packed upper-triangle per batch.
// Compute-bound on the vector ALU (no MFMA possible: op is not bilinear).

#define NB 64
#define DD 256
#define MM 100
#define TILE 64
#define NUT 10                 // upper tile-pairs for 4x4 tile grid
#define TRI_PER_B 32896        // D*(D+1)/2
#define NBLK (NB * NUT)        // 640

__device__ __forceinline__ void tile_coords(int t, int& ti, int& tj) {
    // upper pairs in row-major order: (0,0),(0,1),(0,2),(0,3),(1,1),...,(3,3)
    int a = (t >= 4) + (t >= 7) + (t >= 9);
    int s = (a * (9 - a)) >> 1;   // row start: 0,4,7,9
    ti = a;
    tj = t - s + a;
}

// Stage 64 rows x 100 floats into LDS [m][64] (m-major).
// Mapping: il = l4 % 64 (lane id within wave) -> LDS writes are 2-way/bank = free.
// Global: each lane reads float4 of its own row -> every 16B read exactly once.
__device__ __forceinline__ void stage(const float* __restrict__ src,
                                      float (*dst)[TILE], int t) {
    #pragma unroll
    for (int it = 0; it < 7; ++it) {
        int l4 = t + it * 256;
        if (l4 < TILE * MM / 4) {
            int il = l4 & 63;
            int mq = l4 >> 6;                 // 0..24
            float4 v = *reinterpret_cast<const float4*>(src + il * MM + mq * 4);
            int m = mq * 4;
            dst[m + 0][il] = v.x;
            dst[m + 1][il] = v.y;
            dst[m + 2][il] = v.z;
            dst[m + 3][il] = v.w;
        }
    }
}

// Per-thread 4x4 accumulation over all M. 2x ds_read_b128 + 64 VALU per m.
__device__ __forceinline__ void compute_acc(const float (*As)[TILE],
                                            const float (*Bs)[TILE],
                                            int tix, int tiy, float acc[4][4]) {
    #pragma unroll 2
    for (int m = 0; m < MM; ++m) {
        float4 a4 = *reinterpret_cast<const float4*>(&As[m][tix * 4]);
        float4 b4 = *reinterpret_cast<const float4*>(&Bs[m][tiy * 4]);
        float av[4] = {a4.x, a4.y, a4.z, a4.w};
        float bv[4] = {b4.x, b4.y, b4.z, b4.w};
        #pragma unroll
        for (int q = 0; q < 4; ++q) {
            #pragma unroll
            for (int r = 0; r < 4; ++r) {
                float s = av[q] + bv[r];
                float d = av[q] - bv[r];
                acc[q][r] += fabsf(s) - fabsf(d);   // abs folds to input modifier
            }
        }
    }
}

// Pass 1: raw row sums (no scale/0.5) via symmetry + optional tile cache to ws.
extern "C" __global__ void __launch_bounds__(256)
k_rowsum(const float* __restrict__ f, float* __restrict__ rows,
         float* __restrict__ tiles, int store_tiles) {
    __shared__ float As[MM][TILE];
    __shared__ float Bs[MM][TILE];
    const int t = threadIdx.x;
    const int bid = blockIdx.x;
    const int b = bid / NUT;
    const int ut = bid % NUT;
    int ti, tj;
    tile_coords(ut, ti, tj);
    const int i0 = ti * TILE, j0 = tj * TILE;
    const float* fb = f + (size_t)b * DD * MM;

    stage(fb + (size_t)i0 * MM, As, t);
    stage(fb + (size_t)j0 * MM, Bs, t);
    __syncthreads();

    const int tix = t & 15, tiy = t >> 4;
    float acc[4][4] = {};
    compute_acc(As, Bs, tix, tiy, acc);

    if (store_tiles) {
        float* tp = tiles + (size_t)bid * (TILE * TILE);
        #pragma unroll
        for (int q = 0; q < 4; ++q) {
            float4 v = make_float4(acc[q][0], acc[q][1], acc[q][2], acc[q][3]);
            *reinterpret_cast<float4*>(tp + (tix * 4 + q) * TILE + tiy * 4) = v;
        }
    }

    // per-thread partial reductions
    float ra[4], cb[4];
    #pragma unroll
    for (int q = 0; q < 4; ++q)
        ra[q] = acc[q][0] + acc[q][1] + acc[q][2] + acc[q][3];
    #pragma unroll
    for (int r = 0; r < 4; ++r)
        cb[r] = acc[0][r] + acc[1][r] + acc[2][r] + acc[3][r];

    __syncthreads();                     // done with As/Bs data, reuse as scratch
    float* red  = &As[0][0];             // [16][64]: row contributions
    float* red2 = &Bs[0][0];             // [16][64]: col contributions
    #pragma unroll
    for (int q = 0; q < 4; ++q) red[tiy * 64 + tix * 4 + q] = ra[q];
    #pragma unroll
    for (int r = 0; r < 4; ++r) red2[tix * 64 + tiy * 4 + r] = cb[r];
    __syncthreads();

    if (t < TILE) {
        float s = 0.f;
        #pragma unroll
        for (int w = 0; w < 16; ++w) s += red[w * 64 + t];
        atomicAdd(&rows[b * DD + i0 + t], s);
    } else if (t < 2 * TILE && ti != tj) {
        int u = t - TILE;
        float s = 0.f;
        #pragma unroll
        for (int w = 0; w < 16; ++w) s += red2[w * 64 + u];
        atomicAdd(&rows[b * DD + j0 + u], s);   // symmetric contribution
    }
}

// Pass 2: center + scale + triu-pack. Uses cached tiles when available.
extern "C" __global__ void __launch_bounds__(256)
k_out(const float* __restrict__ f, const float* __restrict__ rows,
      const float* __restrict__ temp, const float* __restrict__ tiles,
      int use_tiles, float* __restrict__ out) {
    __shared__ float As[MM][TILE];
    __shared__ float Bs[MM][TILE];
    const int t = threadIdx.x;
    const int bid = blockIdx.x;
    const int b = bid / NUT;
    const int ut = bid % NUT;
    int ti, tj;
    tile_coords(ut, ti, tj);
    const int i0 = ti * TILE, j0 = tj * TILE;
    const int tix = t & 15, tiy = t >> 4;

    float acc[4][4];
    if (use_tiles) {
        const float* tp = tiles + (size_t)bid * (TILE * TILE);
        #pragma unroll
        for (int q = 0; q < 4; ++q) {
            float4 v = *reinterpret_cast<const float4*>(tp + (tix * 4 + q) * TILE + tiy * 4);
            acc[q][0] = v.x; acc[q][1] = v.y; acc[q][2] = v.z; acc[q][3] = v.w;
        }
    } else {
        const float* fb = f + (size_t)b * DD * MM;
        stage(fb + (size_t)i0 * MM, As, t);
        stage(fb + (size_t)j0 * MM, Bs, t);
        __syncthreads();
        #pragma unroll
        for (int q = 0; q < 4; ++q)
            #pragma unroll
            for (int r = 0; r < 4; ++r) acc[q][r] = 0.f;
        compute_acc(As, Bs, tix, tiy, acc);
    }

    const float scale = 0.5f * expf(temp[0]);
    const float inv_d = 1.0f / DD;
    float rloc[4], cloc[4];
    #pragma unroll
    for (int q = 0; q < 4; ++q) rloc[q] = rows[b * DD + i0 + tix * 4 + q];
    #pragma unroll
    for (int r = 0; r < 4; ++r) cloc[r] = rows[b * DD + j0 + tiy * 4 + r];

    float* ob = out + (size_t)b * TRI_PER_B;
    #pragma unroll
    for (int q = 0; q < 4; ++q) {
        const int i = i0 + tix * 4 + q;
        #pragma unroll
        for (int r = 0; r < 4; ++r) {
            const int j = j0 + tiy * 4 + r;
            if (j >= i) {
                const int off = (i * (2 * DD - i + 1)) / 2 + (j - i);
                ob[off] = scale * (acc[q][r] - (rloc[q] + cloc[r]) * inv_d);
            }
        }
    }
}

extern "C" void kernel_launch(void* const* d_in, const int* in_sizes, int n_in,
                              void* d_out, int out_size, void* d_ws, size_t ws_size,
                              hipStream_t stream) {
    const float* f    = (const float*)d_in[0];
    const float* temp = (const float*)d_in[1];
    float* out  = (float*)d_out;
    float* rows = (float*)d_ws;                       // 64*256 floats = 64 KB

    const size_t rows_bytes  = (size_t)NB * DD * sizeof(float);
    const size_t tiles_bytes = (size_t)NBLK * TILE * TILE * sizeof(float); // 10.5 MB
    const int cached = (ws_size >= rows_bytes + tiles_bytes) ? 1 : 0;
    float* tiles = rows + NB * DD;

    hipMemsetAsync(rows, 0, rows_bytes, stream);
    k_rowsum<<<NBLK, 256, 0, stream>>>(f, rows, tiles, cached);
    k_out<<<NBLK, 256, 0, stream>>>(f, rows, temp, tiles, cached, out);
}

// Round 2
// 59.074 us; speedup vs baseline: 1.0661x; 1.0661x over previous
//
#include <hip/hip_runtime.h>

// B=64, D=256, M=100
//   k(b,i,j) = 0.5 * sum_m (|f_i+f_j| - |f_i-f_j|) * exp(T)
//   out = k - rowmean_i - rowmean_j (symmetric), triu-packed per batch.
// VALU-bound (no MFMA possible). Split-M (52/48) -> 1280 blocks for occupancy.

#define NB 64
#define DD 256
#define MM 100
#define TILE 64
#define NUT 10                 // upper 64x64 tile-pairs of a 4x4 tile grid
#define TRI_PER_B 32896        // D*(D+1)/2
#define NTILE 640              // NB * NUT
#define NM0 52                 // first M-chunk (13 float4)
#define TILE_F (TILE * TILE)   // 4096 floats per tile

__device__ __forceinline__ void tile_coords(int t, int& ti, int& tj) {
    int a = (t >= 4) + (t >= 7) + (t >= 9);
    int s = (a * (9 - a)) >> 1;   // 0,4,7,9
    ti = a;
    tj = t - s + a;
}

// Stage 64 rows x nmq float4 (M-chunk) into LDS [m][64].
__device__ __forceinline__ void stage_chunk(const float* __restrict__ src,
                                            float (*dst)[TILE], int t,
                                            int m0, int nmq) {
    const int total = TILE * nmq;              // 832 or 768
    for (int l4 = t; l4 < total; l4 += 256) {
        int il = l4 & 63;
        int mq = l4 >> 6;
        float4 v = *reinterpret_cast<const float4*>(src + (size_t)il * MM + m0 + mq * 4);
        int m = mq * 4;
        dst[m + 0][il] = v.x;
        dst[m + 1][il] = v.y;
        dst[m + 2][il] = v.z;
        dst[m + 3][il] = v.w;
    }
}

// Pass 1: partial 64x64 tiles over one M-chunk + raw row-sum atomics.
extern "C" __global__ void __launch_bounds__(256, 8)
k_partial(const float* __restrict__ f, float* __restrict__ rows,
          float* __restrict__ tiles, int atomic_mode) {
    __shared__ float As[NM0][TILE];   // 13.0 KB
    __shared__ float Bs[NM0][TILE];   // total 26.0 KB -> 6 blocks/CU
    const int t = threadIdx.x;
    const int bid = blockIdx.x;       // 0..1279
    const int h = bid & 1;            // M-half (interleaved for balance)
    const int bt = bid >> 1;          // 0..639 tile id
    const int b = bt / NUT;
    const int ut = bt % NUT;
    int ti, tj;
    tile_coords(ut, ti, tj);
    const int i0 = ti * TILE, j0 = tj * TILE;
    const int m0 = h ? NM0 : 0;
    const int nm = h ? (MM - NM0) : NM0;   // 48 or 52 (both %4==0)
    const float* fb = f + (size_t)b * DD * MM;

    stage_chunk(fb + (size_t)i0 * MM, As, t, m0, nm >> 2);
    stage_chunk(fb + (size_t)j0 * MM, Bs, t, m0, nm >> 2);
    __syncthreads();

    const int tix = t & 15, tiy = t >> 4;
    float acc[4][4] = {};
    #pragma unroll 2
    for (int m = 0; m < nm; ++m) {
        float4 a4 = *reinterpret_cast<const float4*>(&As[m][tix * 4]);
        float4 b4 = *reinterpret_cast<const float4*>(&Bs[m][tiy * 4]);
        float av[4] = {a4.x, a4.y, a4.z, a4.w};
        float bv[4] = {b4.x, b4.y, b4.z, b4.w};
        #pragma unroll
        for (int q = 0; q < 4; ++q) {
            #pragma unroll
            for (int r = 0; r < 4; ++r) {
                float s = av[q] + bv[r];
                float d = av[q] - bv[r];
                acc[q][r] += fabsf(s) - fabsf(d);   // abs folds to input modifiers
            }
        }
    }

    // partial tile -> workspace
    if (atomic_mode) {
        float* tp = tiles + (size_t)bt * TILE_F;
        #pragma unroll
        for (int q = 0; q < 4; ++q)
            #pragma unroll
            for (int r = 0; r < 4; ++r)
                atomicAdd(tp + (tix * 4 + q) * TILE + tiy * 4 + r, acc[q][r]);
    } else {
        float* tp = tiles + ((size_t)h * NTILE + bt) * TILE_F;
        #pragma unroll
        for (int q = 0; q < 4; ++q) {
            float4 v = make_float4(acc[q][0], acc[q][1], acc[q][2], acc[q][3]);
            *reinterpret_cast<float4*>(tp + (tix * 4 + q) * TILE + tiy * 4) = v;
        }
    }

    // row-sum partials (and col partials for off-diag tiles via symmetry)
    float ra[4], cb[4];
    #pragma unroll
    for (int q = 0; q < 4; ++q)
        ra[q] = acc[q][0] + acc[q][1] + acc[q][2] + acc[q][3];
    #pragma unroll
    for (int r = 0; r < 4; ++r)
        cb[r] = acc[0][r] + acc[1][r] + acc[2][r] + acc[3][r];

    __syncthreads();                       // As/Bs reads done; reuse as scratch
    float* red  = &As[0][0];               // [16][64]
    float* red2 = &Bs[0][0];
    #pragma unroll
    for (int q = 0; q < 4; ++q) red[tiy * 64 + tix * 4 + q] = ra[q];
    #pragma unroll
    for (int r = 0; r < 4; ++r) red2[tix * 64 + tiy * 4 + r] = cb[r];
    __syncthreads();

    if (t < TILE) {
        float s = 0.f;
        #pragma unroll
        for (int w = 0; w < 16; ++w) s += red[w * 64 + t];
        atomicAdd(&rows[b * DD + i0 + t], s);
    } else if (t < 2 * TILE && ti != tj) {
        int u = t - TILE;
        float s = 0.f;
        #pragma unroll
        for (int w = 0; w < 16; ++w) s += red2[w * 64 + u];
        atomicAdd(&rows[b * DD + j0 + u], s);
    }
}

// Pass 2: combine slices, center, scale, triu-pack. No LDS, coalesced stores.
extern "C" __global__ void __launch_bounds__(256)
k_finalize(const float* __restrict__ rows, const float* __restrict__ temp,
           const float* __restrict__ tiles, int nslice, float* __restrict__ out) {
    const int t = threadIdx.x;
    const int bt = blockIdx.x;        // 0..639
    const int b = bt / NUT;
    const int ut = bt % NUT;
    int ti, tj;
    tile_coords(ut, ti, tj);
    const int i0 = ti * TILE, j0 = tj * TILE;
    // tix = row group (t>>4) so consecutive lanes cover consecutive cols
    const int tix = t >> 4, tiy = t & 15;

    const float* t0 = tiles + (size_t)bt * TILE_F;
    const float* t1 = tiles + ((size_t)NTILE + bt) * TILE_F;

    float acc[4][4];
    #pragma unroll
    for (int q = 0; q < 4; ++q) {
        const int off = (tix * 4 + q) * TILE + tiy * 4;
        float4 v = *reinterpret_cast<const float4*>(t0 + off);
        acc[q][0] = v.x; acc[q][1] = v.y; acc[q][2] = v.z; acc[q][3] = v.w;
        if (nslice == 2) {
            float4 w = *reinterpret_cast<const float4*>(t1 + off);
            acc[q][0] += w.x; acc[q][1] += w.y; acc[q][2] += w.z; acc[q][3] += w.w;
        }
    }

    const float scale = 0.5f * expf(temp[0]);
    const float inv_d = 1.0f / DD;
    float rloc[4], cloc[4];
    #pragma unroll
    for (int q = 0; q < 4; ++q) rloc[q] = rows[b * DD + i0 + tix * 4 + q];
    #pragma unroll
    for (int r = 0; r < 4; ++r) cloc[r] = rows[b * DD + j0 + tiy * 4 + r];

    float* ob = out + (size_t)b * TRI_PER_B;
    #pragma unroll
    for (int q = 0; q < 4; ++q) {
        const int i = i0 + tix * 4 + q;
        float v[4];
        #pragma unroll
        for (int r = 0; r < 4; ++r)
            v[r] = scale * (acc[q][r] - (rloc[q] + cloc[r]) * inv_d);
        const int j0e = j0 + tiy * 4;
        if (ti != tj) {  // whole float4 is in the triangle, contiguous in out
            const int off = (i * (2 * DD - i + 1)) / 2 + (j0e - i);
            *reinterpret_cast<float4*>(ob + off) = make_float4(v[0], v[1], v[2], v[3]);
        } else {
            #pragma unroll
            for (int r = 0; r < 4; ++r) {
                const int j = j0e + r;
                if (j >= i) {
                    const int off = (i * (2 * DD - i + 1)) / 2 + (j - i);
                    ob[off] = v[r];
                }
            }
        }
    }
}

extern "C" void kernel_launch(void* const* d_in, const int* in_sizes, int n_in,
                              void* d_out, int out_size, void* d_ws, size_t ws_size,
                              hipStream_t stream) {
    const float* f    = (const float*)d_in[0];
    const float* temp = (const float*)d_in[1];
    float* out  = (float*)d_out;
    float* rows = (float*)d_ws;                       // 64 KB
    float* tiles = rows + NB * DD;

    const size_t rows_b   = (size_t)NB * DD * sizeof(float);
    const size_t tile_b   = (size_t)NTILE * TILE_F * sizeof(float);  // 10.5 MB
    const size_t need2    = rows_b + 2 * tile_b;                     // 21.0 MB

    hipMemsetAsync(rows, 0, rows_b, stream);
    if (ws_size >= need2) {
        k_partial<<<2 * NTILE, 256, 0, stream>>>(f, rows, tiles, 0);
        k_finalize<<<NTILE, 256, 0, stream>>>(rows, temp, tiles, 2, out);
    } else {
        hipMemsetAsync(tiles, 0, tile_b, stream);
        k_partial<<<2 * NTILE, 256, 0, stream>>>(f, rows, tiles, 1);
        k_finalize<<<NTILE, 256, 0, stream>>>(rows, temp, tiles, 1, out);
    }
}